// Round 12
// baseline (276.214 us; speedup 1.0000x reference)
//
#include <hip/hip_runtime.h>

// Non-local attention, B=1,C=3,H=W=128,k=3 -> L=15876 patches, d=27
#define LQv  15876
#define LP   16384              // padded keys: 1024 tiles of 16
#define LQP  16384              // padded queries
#define HOc  126
#define NCH  16                 // attn split-K chunks (1024 keys each)
// exp2-arg = C2L*(q.k) + ck[key] + (80 - CKS*yy)[query] = 80 - CKS*||q-k||^2
// all folded into MFMA pad dims (see prep).
#define C2L  8.243971662222648f
#define IC2L 0.1213006672795172f
#define CKS  4.121985831111324f

typedef __attribute__((ext_vector_type(8))) short bf16x8;
typedef __attribute__((ext_vector_type(4))) float f32x4;

#define MFMA(a,b,c) __builtin_amdgcn_mfma_f32_16x16x32_bf16((a),(b),(c),0,0,0)
#define EXP2(x) __builtin_amdgcn_exp2f(x)

__device__ __forceinline__ unsigned short f2bf_rne(float f) {
    unsigned u = __float_as_uint(f);
    unsigned r = ((u >> 16) & 1u) + 0x7FFFu;
    return (unsigned short)((u + r) >> 16);
}
__device__ __forceinline__ float bf2f(unsigned short h) {
    return __uint_as_float(((unsigned)h) << 16);
}
__device__ __forceinline__ void split_bf(float v, unsigned short& hi, unsigned short& lo) {
    hi = f2bf_rne(v);
    lo = f2bf_rne(v - bf2f(hi));
}
__device__ __forceinline__ constexpr int doffc(int d) {
    return (d / 9) * 16384 + ((d % 9) / 3) * 128 + ((d % 9) % 3);
}

// ---------------------------------------------------------------------------
// R11 POST-MORTEM: absmax 2.55 == max|ref| -> output all zeros -> the
// cooperative launch NEVER RAN. kernel_launch executes under stream capture
// (Guideline 9) and hipLaunchCooperativeKernel is not graph-capturable ->
// silent error, no dispatch. The fusion idea was untested.
// THIS ROUND: same fusion, capture-safe. Hand-rolled grid barrier with
// device-scope atomics (m20):
//   - co-residency: 512 blocks (attn does 2 chunks/block, Q regs reused);
//     need 2 blocks/CU, static capacity 6 (LDS) / 4 (VGPR<=128), and R8's
//     counters showed >=2.3 concurrent -> no deadlock.
//   - counter init: hipMemsetAsync(out,0,8,stream) before the kernel
//     (async, capturable; the harness's own test uses it). Counters in
//     out[0..1], overwritten by final with real pixels at the end; spin
//     threshold >=512 is robust (any normal float uint-pattern >> 512).
//   - cross-XCD: release = syncthreads(vmcnt drain)+threadfence+RELEASE add;
//     acquire = ACQUIRE load+threadfence. Inter-phase data is deterministic
//     per launch, so stale-line reads reproduce identical values.
// Phase bodies verbatim R8 (best: 120.8us total, attn 57.8).
// ---------------------------------------------------------------------------

__device__ __forceinline__ void bar_arrive(unsigned* c) {
    __syncthreads();                              // block stores drained (vmcnt)
    if (threadIdx.x == 0) {
        __threadfence();                          // release: XCD L2 writeback
        __hip_atomic_fetch_add(c, 1u, __ATOMIC_RELEASE, __HIP_MEMORY_SCOPE_AGENT);
    }
}
__device__ __forceinline__ void bar_wait(unsigned* c, unsigned n) {
    if (threadIdx.x == 0) {
        while (__hip_atomic_load(c, __ATOMIC_ACQUIRE, __HIP_MEMORY_SCOPE_AGENT) < n)
            __builtin_amdgcn_s_sleep(8);
        __threadfence();                          // acquire: invalidate caches
    }
    __syncthreads();
}

// ---- phase 1: prep (blocks 0..383), verbatim R8 ---------------------------
__device__ __forceinline__ void prep_phase(int bid, int tid,
    const float* __restrict__ x, const float* __restrict__ y,
    unsigned short* __restrict__ khi, unsigned short* __restrict__ klo,
    unsigned short* __restrict__ qhi, unsigned short* __restrict__ qlo,
    unsigned short* __restrict__ vt)
{
    int gidx = bid * 256 + tid;                  // 384*256 = 98304 threads
    int pair = gidx >> 1, half = gidx & 1;
    int l = pair & (LP - 1);
    int role = pair >> 14;                       // block-uniform (128 blk/role)
    bool real = l < LQv;
    int i = real ? (l / HOc) : 0, j = real ? (l - i * HOc) : 0;
    int base = i * 128 + j;

    if (role < 2) {
        const float* __restrict__ src = role ? y : x;
        float scale = role ? C2L : 1.f;
        __align__(16) unsigned short hh[16], ll[16];
        float ss = 0.f;
#pragma unroll
        for (int it = 0; it < 16; ++it) {
            int offL = doffc(it);
            int offH = (16 + it < 27) ? doffc(16 + it) : 0;
            int off  = half ? offH : offL;
            bool ok  = (it < 11) ? real : (real && !half);
            float v = src[base + off];
            v = ok ? v : 0.f;
            ss = fmaf(v, v, ss);
            split_bf(scale * v, hh[it], ll[it]);
        }
        float tot = ss + __shfl_xor(ss, 1);      // full ||row||^2
        if (half) {                              // pad dims 27..31 = idx 11..15
            if (role == 0) {
                float ckv = real ? (-tot * CKS) : -1e30f;  // pad keys -> p=0
                split_bf(ckv * IC2L, hh[11], ll[11]);
                hh[12] = ll[12] = 0;
                hh[13] = 0x3F80; ll[13] = 0;     // bf16(1.0)
                hh[14] = ll[14] = 0; hh[15] = ll[15] = 0;
            } else {
                split_bf(C2L, hh[11], ll[11]);
                hh[12] = ll[12] = 0;
                split_bf(80.f - CKS * tot, hh[13], ll[13]);  // analytic shift
                hh[14] = ll[14] = 0; hh[15] = ll[15] = 0;
            }
        }
        int d0 = half << 4;
        unsigned short* dh = (role ? qhi : khi) + (size_t)l * 32 + d0;
        unsigned short* dl = (role ? qlo : klo) + (size_t)l * 32 + d0;
        ((uint4*)dh)[0] = ((uint4*)hh)[0]; ((uint4*)dh)[1] = ((uint4*)hh)[1];
        ((uint4*)dl)[0] = ((uint4*)ll)[0]; ((uint4*)dl)[1] = ((uint4*)ll)[1];
    } else {                                     // ---- permuted Vt
        int kap = l & 31;
        int cp = 8 * ((kap >> 2) & 3) + 4 * (kap >> 4) + (kap & 3);
        int lp = (l & ~31) | cp;
        unsigned short* vbase = vt + lp + (half ? 16 * LP : 0);
#pragma unroll
        for (int it = 0; it < 16; ++it) {
            int offL = doffc(it);
            int offH = (16 + it < 27) ? doffc(16 + it) : 0;
            int off  = half ? offH : offL;
            bool ok  = (it < 11) ? real : (real && !half);
            float xv = x[base + off];
            unsigned short v;
            if (it == 11)  // half1 col 27: ones row -> lsum column
                v = ok ? f2bf_rne(xv) : ((real && half) ? (unsigned short)0x3F80
                                                        : (unsigned short)0);
            else
                v = ok ? f2bf_rne(xv) : 0;
            vbase[it * LP] = v;
        }
    }
}

// ---- phase 2: attn (all 512 blocks, 2 chunks each), R8 body ---------------
__device__ __forceinline__ void gload16(const unsigned short* g, unsigned short* l)
{
    __builtin_amdgcn_global_load_lds(
        (__attribute__((address_space(1))) void*)g,
        (__attribute__((address_space(3))) void*)l, 16, 0, 0);
}
// swizzled per-lane source offset (u16 units) for row-major K segments:
// row R=lane>>2 keeps its 32-u16 row; 8-u16 chunk C=lane&3 XOR s(R)=(lane>>3)&3
#define SLANE8(lane) ((((lane) & ~3) | (((lane) & 3) ^ (((lane) >> 3) & 3))) * 8)
#define SCHUNK8(lane) ((((lane) & 3) ^ (((lane) >> 3) & 3)) * 8)

__device__ __forceinline__ void attn_phase(int bid, int tid, unsigned short* lds,
    const unsigned short* __restrict__ khi, const unsigned short* __restrict__ klo,
    const unsigned short* __restrict__ qhi, const unsigned short* __restrict__ qlo,
    const unsigned short* __restrict__ vt,  unsigned int* __restrict__ opart)
{
    // 64-key buffer: khi [64][32] @0, klo @2048, vt 2x[32][32] @4096/@5120
    int lane = tid & 63;
    int wave = tid >> 6;
    int n = lane & 15, g = lane >> 4;
    int gx = g ^ ((n >> 1) & 3);                 // swizzled read chunk
    int qbx = bid & 63, chp = bid >> 6;          // chp in 0..7
    int qb = qbx * 256 + wave * 64;

    bf16x8 bqh[4], bql[4];                       // Q loaded ONCE for 2 chunks
#pragma unroll
    for (int t = 0; t < 4; ++t) {
        bqh[t] = *(const bf16x8*)(qhi + (size_t)(qb + t * 16 + n) * 32 + g * 8);
        bql[t] = *(const bf16x8*)(qlo + (size_t)(qb + t * 16 + n) * 32 + g * 8);
    }

    unsigned short* B0 = lds;
    unsigned short* B1 = lds + 6144;

#define STAGE(dst, kb) do {                                                   \
        if (wave == 0) {                                                      \
            gload16(khi + (size_t)(kb) * 32 +        SLANE8(lane), (dst));    \
            gload16(khi + (size_t)(kb) * 32 +  512 + SLANE8(lane), (dst) + 512);\
            gload16(khi + (size_t)(kb) * 32 + 1024 + SLANE8(lane), (dst) + 1024);\
            gload16(khi + (size_t)(kb) * 32 + 1536 + SLANE8(lane), (dst) + 1536);\
        } else if (wave == 1) {                                               \
            gload16(klo + (size_t)(kb) * 32 +        SLANE8(lane), (dst) + 2048);\
            gload16(klo + (size_t)(kb) * 32 +  512 + SLANE8(lane), (dst) + 2560);\
            gload16(klo + (size_t)(kb) * 32 + 1024 + SLANE8(lane), (dst) + 3072);\
            gload16(klo + (size_t)(kb) * 32 + 1536 + SLANE8(lane), (dst) + 3584);\
        } else if (wave == 2) {                                               \
            gload16(vt + (size_t)(lane >> 2) * LP + (kb) + SCHUNK8(lane),     \
                    (dst) + 4096);                                            \
            gload16(vt + (size_t)(16 + (lane >> 2)) * LP + (kb) + SCHUNK8(lane), \
                    (dst) + 4608);                                            \
        } else {                                                              \
            gload16(vt + (size_t)(lane >> 2) * LP + (kb) + 32 + SCHUNK8(lane),\
                    (dst) + 5120);                                            \
            gload16(vt + (size_t)(16 + (lane >> 2)) * LP + (kb) + 32 + SCHUNK8(lane), \
                    (dst) + 5632);                                            \
        }                                                                     \
    } while (0)

    for (int cc = 0; cc < 2; ++cc) {
        int ch = chp + cc * 8;
        int kb0 = ch * 1024;

        f32x4 o0[4], o1[4];
#pragma unroll
        for (int t = 0; t < 4; ++t) {
            o0[t] = (f32x4){0.f, 0.f, 0.f, 0.f};
            o1[t] = (f32x4){0.f, 0.f, 0.f, 0.f};
        }

        STAGE(B0, kb0);
        __syncthreads();

        for (int it = 0; it < 16; ++it) {        // 16 x 64-key tiles
            int kbn = kb0 + ((it + 1) & 15) * 64;
            unsigned short* cur = (it & 1) ? B1 : B0;
            unsigned short* nxt = (it & 1) ? B0 : B1;
            STAGE(nxt, kbn);
            __builtin_amdgcn_sched_barrier(0);   // pin load-issue at region top

            const unsigned short* L = cur;
#pragma unroll
            for (int h = 0; h < 2; ++h) {        // two 32-key halves
                bf16x8 kh0 = *(const bf16x8*)(L + (32 * h + n) * 32 + gx * 8);
                bf16x8 kh1 = *(const bf16x8*)(L + (32 * h + 16 + n) * 32 + gx * 8);
                bf16x8 kl0 = *(const bf16x8*)(L + 2048 + (32 * h + n) * 32 + gx * 8);
                bf16x8 kl1 = *(const bf16x8*)(L + 2048 + (32 * h + 16 + n) * 32 + gx * 8);
                bf16x8 v0  = *(const bf16x8*)(L + 4096 + h * 1024 + n * 32 + gx * 8);
                bf16x8 v1  = *(const bf16x8*)(L + 4096 + h * 1024 + (16 + n) * 32 + gx * 8);

#pragma unroll
                for (int qt = 0; qt < 4; ++qt) {
                    f32x4 cc0 = {0.f, 0.f, 0.f, 0.f}, cc1 = {0.f, 0.f, 0.f, 0.f};
                    cc0 = MFMA(kh0, bqh[qt], cc0); cc1 = MFMA(kh1, bqh[qt], cc1);
                    cc0 = MFMA(kh0, bql[qt], cc0); cc1 = MFMA(kh1, bql[qt], cc1);
                    cc0 = MFMA(kl0, bqh[qt], cc0); cc1 = MFMA(kl1, bqh[qt], cc1);
                    // accumulator IS the exp2 argument (all consts folded)
                    float p0 = EXP2(cc0[0]);
                    float p1 = EXP2(cc0[1]);
                    float p2 = EXP2(cc0[2]);
                    float p3 = EXP2(cc0[3]);
                    float p4 = EXP2(cc1[0]);
                    float p5 = EXP2(cc1[1]);
                    float p6 = EXP2(cc1[2]);
                    float p7 = EXP2(cc1[3]);
                    // packed p-pairs ARE the PV A-fragment (Vt perm'd in prep)
                    union { unsigned u[4]; bf16x8 v; } ap;
                    ap.u[0] = __builtin_amdgcn_perm(__float_as_uint(p1), __float_as_uint(p0), 0x07060302u);
                    ap.u[1] = __builtin_amdgcn_perm(__float_as_uint(p3), __float_as_uint(p2), 0x07060302u);
                    ap.u[2] = __builtin_amdgcn_perm(__float_as_uint(p5), __float_as_uint(p4), 0x07060302u);
                    ap.u[3] = __builtin_amdgcn_perm(__float_as_uint(p7), __float_as_uint(p6), 0x07060302u);
                    o0[qt] = MFMA(ap.v, v0, o0[qt]);
                    o1[qt] = MFMA(ap.v, v1, o1[qt]);
                }
            }
            __syncthreads();  // one vmcnt+lgkm drain per 64-key tile
        }

        // epilogue: bf16-pack partials; u32 index n holds cols (n, n+16)
#pragma unroll
        for (int qt = 0; qt < 4; ++qt) {
#pragma unroll
            for (int r = 0; r < 4; ++r) {
                unsigned w = ((unsigned)f2bf_rne(o1[qt][r]) << 16) | f2bf_rne(o0[qt][r]);
                size_t row = (size_t)ch * LQP + qb + qt * 16 + 4 * g + r;
                opart[row * 16 + n] = w;
            }
        }
        __syncthreads();      // LDS free before next chunk's STAGE
    }
#undef STAGE
}

// ---- phase 3: final (blocks 0..255), verbatim R8 --------------------------
__device__ __forceinline__ void final_phase(int bid, int tid, float* lpatch,
    const unsigned int* __restrict__ opart, float* __restrict__ out)
{
    int lane = tid & 63;
    int h0 = (bid >> 4) * 8, w0 = (bid & 15) * 8;

    for (int t = tid; t < 1600; t += 256) {      // 100 rows x 16 pairs
        int rr = t >> 4, n = t & 15;
        int di = rr / 10, dj = rr - di * 10;
        int I = h0 - 2 + di, J = w0 - 2 + dj;
        bool valid = ((unsigned)I < 126u) && ((unsigned)J < 126u);
        int l = valid ? (I * HOc + J) : 0;       // clamped row never read
        float s0 = 0.f, s1 = 0.f;
#pragma unroll
        for (int c = 0; c < NCH; ++c) {
            unsigned v = opart[((size_t)c * LQP + l) * 16 + n];
            s0 += bf2f((unsigned short)(v & 0xffffu));
            s1 += bf2f((unsigned short)(v >> 16));
        }
        float denom = __shfl(s1, (lane & 48) | 11);  // lsum: pair-11 hi half
        float inv = 1.f / denom;
        lpatch[rr * 32 + n]      = s0 * inv;
        lpatch[rr * 32 + 16 + n] = s1 * inv;
    }
    __syncthreads();

    if (tid < 192) {                             // 3 channels x 64 pixels
        int c = tid >> 6, pix = tid & 63;
        int h = h0 + (pix >> 3), w = w0 + (pix & 7);
        float sum = 0.f; int cnt = 0;
#pragma unroll
        for (int r1 = 0; r1 < 3; ++r1) {
            int I = h - r1; if ((unsigned)I >= 126u) continue;
#pragma unroll
            for (int r2 = 0; r2 < 3; ++r2) {
                int J = w - r2; if ((unsigned)J >= 126u) continue;
                int rr = (I - (h0 - 2)) * 10 + (J - (w0 - 2));
                sum += lpatch[rr * 32 + c * 9 + r1 * 3 + r2];
                ++cnt;
            }
        }
        out[c * 16384 + h * 128 + w] = sum / (float)cnt;
    }
}

// ---------------------------------------------------------------------------
// fused: prep | atomic grid barrier | attn(2 chunks) | barrier | final.
// 512 blocks x 256. Counters in out[0..1] (zeroed by our 8-byte memset each
// launch; final overwrites them with real pixel values at the very end).
// ---------------------------------------------------------------------------
__global__ __launch_bounds__(256, 4) void fused_kernel(
    const float* __restrict__ x, const float* __restrict__ y,
    unsigned short* __restrict__ khi, unsigned short* __restrict__ klo,
    unsigned short* __restrict__ qhi, unsigned short* __restrict__ qlo,
    unsigned short* __restrict__ vt,  unsigned int* __restrict__ opart,
    float* __restrict__ out)
{
    __shared__ __align__(16) unsigned short smem[2][6144];   // 24 KB
    int bid = blockIdx.x, tid = threadIdx.x;
    unsigned* barA = (unsigned*)out;             // out[0], zeroed pre-launch
    unsigned* barB = (unsigned*)out + 1;         // out[1]

    if (bid < 384)
        prep_phase(bid, tid, x, y, khi, klo, qhi, qlo, vt);
    bar_arrive(barA);
    bar_wait(barA, 512);

    attn_phase(bid, tid, &smem[0][0], khi, klo, qhi, qlo, vt, opart);
    bar_arrive(barB);

    if (bid < 256) {
        bar_wait(barB, 512);
        final_phase(bid, tid, (float*)&smem[0][0], opart, out);
    }
}

// ---------------------------------------------------------------------------
extern "C" void kernel_launch(void* const* d_in, const int* in_sizes, int n_in,
                              void* d_out, int out_size, void* d_ws, size_t ws_size,
                              hipStream_t stream)
{
    const float* x = (const float*)d_in[0];
    const float* y = (const float*)d_in[1];
    float* out = (float*)d_out;

    // ws layout (21 MB)
    unsigned short* khi = (unsigned short*)d_ws;          // LP*32 u16 (1 MB)
    unsigned short* klo = khi + (size_t)LP * 32;          // 1 MB
    unsigned short* qhi = klo + (size_t)LP * 32;          // 1 MB
    unsigned short* qlo = qhi + (size_t)LQP * 32;         // 1 MB
    unsigned short* vt  = qlo + (size_t)LQP * 32;         // 1 MB (dim-major, permuted)
    unsigned int* opart = (unsigned int*)(vt + (size_t)32 * LP); // 16 MB

    // zero the barrier counters (out[0..1]) -- async + graph-capturable
    hipMemsetAsync(out, 0, 2 * sizeof(unsigned), stream);

    fused_kernel<<<dim3(512), dim3(256), 0, stream>>>(
        x, y, khi, klo, qhi, qlo, vt, opart, out);
}

// Round 13
// 121.547 us; speedup vs baseline: 2.2725x; 2.2725x over previous
//
#include <hip/hip_runtime.h>

// Non-local attention, B=1,C=3,H=W=128,k=3 -> L=15876 patches, d=27
#define LQv  15876
#define LP   16384              // padded keys: 1024 tiles of 16
#define LQP  16384              // padded queries
#define HOc  126
#define NCH  8                  // attn split-K chunks (2048 keys each)
// exp2-arg = C2L*(q.k) + ck[key] + (80 - CKS*yy)[query] = 80 - CKS*||q-k||^2
// all folded into MFMA pad dims:
//   q dims 0..26 pre-scaled by C2L; key dim27 = ck*IC2L, query dim27 = C2L
//   key dim29 = 1.0, query dim29 = 80 - CKS*yy   (analytic shift)
#define C2L  8.243971662222648f
#define IC2L 0.1213006672795172f
#define CKS  4.121985831111324f

typedef __attribute__((ext_vector_type(8))) short bf16x8;
typedef __attribute__((ext_vector_type(4))) float f32x4;

#define MFMA(a,b,c) __builtin_amdgcn_mfma_f32_16x16x32_bf16((a),(b),(c),0,0,0)
#define EXP2(x) __builtin_amdgcn_exp2f(x)

__device__ __forceinline__ unsigned short f2bf_rne(float f) {
    unsigned u = __float_as_uint(f);
    unsigned r = ((u >> 16) & 1u) + 0x7FFFu;
    return (unsigned short)((u + r) >> 16);
}
__device__ __forceinline__ float bf2f(unsigned short h) {
    return __uint_as_float(((unsigned)h) << 16);
}
__device__ __forceinline__ void split_bf(float v, unsigned short& hi, unsigned short& lo) {
    hi = f2bf_rne(v);
    lo = f2bf_rne(v - bf2f(hi));
}
// compile-time patch-dim -> image offset (relative to i*128+j)
__device__ __forceinline__ constexpr int doffc(int d) {
    return (d / 9) * 16384 + ((d % 9) / 3) * 128 + ((d % 9) % 3);
}

// ---------------------------------------------------------------------------
// R12 POST-MORTEM: fusion definitively refuted -- atomic grid barrier cost
// ~160us (spin on contended cross-XCD line + serialized phases at 2 blk/CU);
// fused 218us vs 3-kernel 120.8. Both fusion routes (cooperative launch is
// not graph-capturable; hand-rolled barrier too slow) are closed.
// THIS ROUND: revert to R8 structure (best), attack the partials traffic:
//   - NCH 16->8 (2048 keys/chunk): opart 16->8MB; attn WRITE halves; final
//     chunk-loop halves. attn grid (64,8)=512=2/CU (R8 ran 2.3 resident;
//     occupancy thrice-refuted as lever) -> attn ~flat. More f32 accum
//     before bf16 rounding -> absmax same or better.
//   - opart transposed to [row][ch][16]: final's per-row chunk loop reads
//     one contiguous 512B run (was 16 x 64B at 1MB stride). attn epilogue
//     writes 64B @ 512B stride (same bytes, amortized over 32 tiles).
// Outcome discriminates the ~63us non-attn residue: drop => final traffic
// was the sink; flat => launch/harness floor (declare converged).
// ---------------------------------------------------------------------------

// ---------------------------------------------------------------------------
// prep: PAIR-SPLIT over 384 blocks (verbatim R8). Roles (128 blk each):
//   role 0: key bf16 hi/lo rows  role 1: query rows (pre-scaled by C2L)
//   role 2: dim-major V, PERMUTED columns (kappa=16t+4g+i -> slot 8g+4t+i)
// ---------------------------------------------------------------------------
__global__ __launch_bounds__(256) void prep_kernel(
    const float* __restrict__ x, const float* __restrict__ y,
    unsigned short* __restrict__ khi, unsigned short* __restrict__ klo,
    unsigned short* __restrict__ qhi, unsigned short* __restrict__ qlo,
    unsigned short* __restrict__ vt)
{
    int gidx = blockIdx.x * 256 + threadIdx.x;   // 384*256 = 98304 threads
    int pair = gidx >> 1, half = gidx & 1;
    int l = pair & (LP - 1);
    int role = pair >> 14;                       // block-uniform (128 blk/role)
    bool real = l < LQv;
    int i = real ? (l / HOc) : 0, j = real ? (l - i * HOc) : 0;
    int base = i * 128 + j;

    if (role < 2) {
        const float* __restrict__ src = role ? y : x;
        float scale = role ? C2L : 1.f;
        __align__(16) unsigned short hh[16], ll[16];
        float ss = 0.f;
#pragma unroll
        for (int it = 0; it < 16; ++it) {
            int offL = doffc(it);
            int offH = (16 + it < 27) ? doffc(16 + it) : 0;
            int off  = half ? offH : offL;
            bool ok  = (it < 11) ? real : (real && !half);
            float v = src[base + off];
            v = ok ? v : 0.f;
            ss = fmaf(v, v, ss);
            split_bf(scale * v, hh[it], ll[it]);
        }
        float tot = ss + __shfl_xor(ss, 1);      // full ||row||^2
        if (half) {                              // pad dims 27..31 = idx 11..15
            if (role == 0) {
                float ckv = real ? (-tot * CKS) : -1e30f;  // pad keys -> p=0
                split_bf(ckv * IC2L, hh[11], ll[11]);
                hh[12] = ll[12] = 0;
                hh[13] = 0x3F80; ll[13] = 0;     // bf16(1.0)
                hh[14] = ll[14] = 0; hh[15] = ll[15] = 0;
            } else {
                split_bf(C2L, hh[11], ll[11]);
                hh[12] = ll[12] = 0;
                split_bf(80.f - CKS * tot, hh[13], ll[13]);  // analytic shift
                hh[14] = ll[14] = 0; hh[15] = ll[15] = 0;
            }
        }
        int d0 = half << 4;
        unsigned short* dh = (role ? qhi : khi) + (size_t)l * 32 + d0;
        unsigned short* dl = (role ? qlo : klo) + (size_t)l * 32 + d0;
        ((uint4*)dh)[0] = ((uint4*)hh)[0]; ((uint4*)dh)[1] = ((uint4*)hh)[1];
        ((uint4*)dl)[0] = ((uint4*)ll)[0]; ((uint4*)dl)[1] = ((uint4*)ll)[1];
    } else {                                     // ---- permuted Vt
        int kap = l & 31;
        int cp = 8 * ((kap >> 2) & 3) + 4 * (kap >> 4) + (kap & 3);
        int lp = (l & ~31) | cp;
        unsigned short* vbase = vt + lp + (half ? 16 * LP : 0);
#pragma unroll
        for (int it = 0; it < 16; ++it) {
            int offL = doffc(it);
            int offH = (16 + it < 27) ? doffc(16 + it) : 0;
            int off  = half ? offH : offL;
            bool ok  = (it < 11) ? real : (real && !half);
            float xv = x[base + off];
            unsigned short v;
            if (it == 11)  // half1 col 27: ones row -> lsum column
                v = ok ? f2bf_rne(xv) : ((real && half) ? (unsigned short)0x3F80
                                                        : (unsigned short)0);
            else
                v = ok ? f2bf_rne(xv) : 0;
            vbase[it * LP] = v;
        }
    }
}

// ---------------------------------------------------------------------------
// attn: R8-proven body. QT=4, LDS double-buffered 64-key tiles, T2 swizzle
// (conflicts 0), one barrier per tile. NCH=8: 32 tiles/chunk, grid (64,8).
// Epilogue writes TRANSPOSED opart [row][ch][16].
// ---------------------------------------------------------------------------
__device__ __forceinline__ void gload16(const unsigned short* g, unsigned short* l)
{
    // lds dest = wave-uniform base + lane*16B; global src is per-lane
    __builtin_amdgcn_global_load_lds(
        (__attribute__((address_space(1))) void*)g,
        (__attribute__((address_space(3))) void*)l, 16, 0, 0);
}

// swizzled per-lane source offset (u16 units) for row-major K segments:
// row R=lane>>2 keeps its 32-u16 row; 8-u16 chunk C=lane&3 XOR s(R)=(lane>>3)&3
#define SLANE8(lane) ((((lane) & ~3) | (((lane) & 3) ^ (((lane) >> 3) & 3))) * 8)
// chunk-only swizzle for vt (row picked separately)
#define SCHUNK8(lane) ((((lane) & 3) ^ (((lane) >> 3) & 3)) * 8)

__global__ __launch_bounds__(256, 4) void attn_kernel(
    const unsigned short* __restrict__ khi, const unsigned short* __restrict__ klo,
    const unsigned short* __restrict__ qhi, const unsigned short* __restrict__ qlo,
    const unsigned short* __restrict__ vt,  unsigned int* __restrict__ opart)
{
    // 64-key buffer: khi [64][32] @0, klo @2048, vt 2x[32][32] @4096/@5120
    __shared__ __align__(16) unsigned short lds[2][6144];  // 24 KB
    int lane = threadIdx.x & 63;
    int wave = threadIdx.x >> 6;
    int n = lane & 15, g = lane >> 4;
    int gx = g ^ ((n >> 1) & 3);                 // swizzled read chunk
    int qb = blockIdx.x * 256 + wave * 64;
    int ch = blockIdx.y;

    bf16x8 bqh[4], bql[4];
#pragma unroll
    for (int t = 0; t < 4; ++t) {
        bqh[t] = *(const bf16x8*)(qhi + (size_t)(qb + t * 16 + n) * 32 + g * 8);
        bql[t] = *(const bf16x8*)(qlo + (size_t)(qb + t * 16 + n) * 32 + g * 8);
    }

    f32x4 o0[4], o1[4];
#pragma unroll
    for (int t = 0; t < 4; ++t) {
        o0[t] = (f32x4){0.f, 0.f, 0.f, 0.f};
        o1[t] = (f32x4){0.f, 0.f, 0.f, 0.f};
    }

    int kb0 = ch * 2048;                         // 2048 keys per chunk

    // ---- stage one 64-key tile (12KB) into dst; 12 x 1KB segments split by
    // wave (w0: khi x4, w1: klo x4, w2: vt half0 x2, w3: vt half1 x2).
    // LDS dest linear (lane*16B); source carries the inverse swizzle.
#define STAGE(dst, kb) do {                                                   \
        if (wave == 0) {                                                      \
            gload16(khi + (size_t)(kb) * 32 +        SLANE8(lane), (dst));    \
            gload16(khi + (size_t)(kb) * 32 +  512 + SLANE8(lane), (dst) + 512);\
            gload16(khi + (size_t)(kb) * 32 + 1024 + SLANE8(lane), (dst) + 1024);\
            gload16(khi + (size_t)(kb) * 32 + 1536 + SLANE8(lane), (dst) + 1536);\
        } else if (wave == 1) {                                               \
            gload16(klo + (size_t)(kb) * 32 +        SLANE8(lane), (dst) + 2048);\
            gload16(klo + (size_t)(kb) * 32 +  512 + SLANE8(lane), (dst) + 2560);\
            gload16(klo + (size_t)(kb) * 32 + 1024 + SLANE8(lane), (dst) + 3072);\
            gload16(klo + (size_t)(kb) * 32 + 1536 + SLANE8(lane), (dst) + 3584);\
        } else if (wave == 2) {                                               \
            gload16(vt + (size_t)(lane >> 2) * LP + (kb) + SCHUNK8(lane),     \
                    (dst) + 4096);                                            \
            gload16(vt + (size_t)(16 + (lane >> 2)) * LP + (kb) + SCHUNK8(lane), \
                    (dst) + 4608);                                            \
        } else {                                                              \
            gload16(vt + (size_t)(lane >> 2) * LP + (kb) + 32 + SCHUNK8(lane),\
                    (dst) + 5120);                                            \
            gload16(vt + (size_t)(16 + (lane >> 2)) * LP + (kb) + 32 + SCHUNK8(lane), \
                    (dst) + 5632);                                            \
        }                                                                     \
    } while (0)

    STAGE(lds[0], kb0);
    __syncthreads();

    int buf = 0;
    for (int it = 0; it < 32; ++it) {            // 32 x 64-key tiles
        // prefetch next tile into the other buffer (wraps at end; dead write)
        int kbn = kb0 + ((it + 1) & 31) * 64;
        STAGE(lds[buf ^ 1], kbn);
        __builtin_amdgcn_sched_barrier(0);       // pin load-issue at region top

        const unsigned short* L = lds[buf];
#pragma unroll
        for (int h = 0; h < 2; ++h) {            // two 32-key halves
            bf16x8 kh0 = *(const bf16x8*)(L + (32 * h + n) * 32 + gx * 8);
            bf16x8 kh1 = *(const bf16x8*)(L + (32 * h + 16 + n) * 32 + gx * 8);
            bf16x8 kl0 = *(const bf16x8*)(L + 2048 + (32 * h + n) * 32 + gx * 8);
            bf16x8 kl1 = *(const bf16x8*)(L + 2048 + (32 * h + 16 + n) * 32 + gx * 8);
            bf16x8 v0  = *(const bf16x8*)(L + 4096 + h * 1024 + n * 32 + gx * 8);
            bf16x8 v1  = *(const bf16x8*)(L + 4096 + h * 1024 + (16 + n) * 32 + gx * 8);

#pragma unroll
            for (int qt = 0; qt < 4; ++qt) {
                f32x4 cc0 = {0.f, 0.f, 0.f, 0.f}, cc1 = {0.f, 0.f, 0.f, 0.f};
                cc0 = MFMA(kh0, bqh[qt], cc0); cc1 = MFMA(kh1, bqh[qt], cc1);
                cc0 = MFMA(kh0, bql[qt], cc0); cc1 = MFMA(kh1, bql[qt], cc1);
                cc0 = MFMA(kl0, bqh[qt], cc0); cc1 = MFMA(kl1, bqh[qt], cc1);
                // accumulator IS the exp2 argument (all consts folded)
                float p0 = EXP2(cc0[0]);
                float p1 = EXP2(cc0[1]);
                float p2 = EXP2(cc0[2]);
                float p3 = EXP2(cc0[3]);
                float p4 = EXP2(cc1[0]);
                float p5 = EXP2(cc1[1]);
                float p6 = EXP2(cc1[2]);
                float p7 = EXP2(cc1[3]);
                // packed p-pairs ARE the PV A-fragment (Vt columns permuted)
                union { unsigned u[4]; bf16x8 v; } ap;
                ap.u[0] = __builtin_amdgcn_perm(__float_as_uint(p1), __float_as_uint(p0), 0x07060302u);
                ap.u[1] = __builtin_amdgcn_perm(__float_as_uint(p3), __float_as_uint(p2), 0x07060302u);
                ap.u[2] = __builtin_amdgcn_perm(__float_as_uint(p5), __float_as_uint(p4), 0x07060302u);
                ap.u[3] = __builtin_amdgcn_perm(__float_as_uint(p7), __float_as_uint(p6), 0x07060302u);
                o0[qt] = MFMA(ap.v, v0, o0[qt]);
                o1[qt] = MFMA(ap.v, v1, o1[qt]);
            }
        }
        __syncthreads();      // one vmcnt+lgkm drain per 64-key tile
        buf ^= 1;
    }
#undef STAGE

    // epilogue: bf16-pack partials, TRANSPOSED layout [row][ch][16]
#pragma unroll
    for (int qt = 0; qt < 4; ++qt) {
#pragma unroll
        for (int r = 0; r < 4; ++r) {
            unsigned w = ((unsigned)f2bf_rne(o1[qt][r]) << 16) | f2bf_rne(o0[qt][r]);
            size_t row = (size_t)(qb + qt * 16 + 4 * g + r);
            opart[(row * NCH + ch) * 16 + n] = w;
        }
    }
}

// ---------------------------------------------------------------------------
// final: FUSED merge + overlap-add (R8 structure). With transposed opart,
// each task's chunk-loop reads one contiguous 512B run per row l.
// ---------------------------------------------------------------------------
__global__ __launch_bounds__(256) void final_kernel(
    const unsigned int* __restrict__ opart, float* __restrict__ out)
{
    __shared__ float lpatch[100 * 32];           // 10x10 rows x 32 cols (12.8 KB)
    int tid = threadIdx.x;
    int lane = tid & 63;
    int h0 = (blockIdx.x >> 4) * 8, w0 = (blockIdx.x & 15) * 8;

    for (int t = tid; t < 1600; t += 256) {      // 100 rows x 16 pairs
        int rr = t >> 4, n = t & 15;
        int di = rr / 10, dj = rr - di * 10;
        int I = h0 - 2 + di, J = w0 - 2 + dj;
        bool valid = ((unsigned)I < 126u) && ((unsigned)J < 126u);
        int l = valid ? (I * HOc + J) : 0;       // clamped row never read
        float s0 = 0.f, s1 = 0.f;
#pragma unroll
        for (int c = 0; c < NCH; ++c) {
            unsigned v = opart[((size_t)l * NCH + c) * 16 + n];
            s0 += bf2f((unsigned short)(v & 0xffffu));
            s1 += bf2f((unsigned short)(v >> 16));
        }
        float denom = __shfl(s1, (lane & 48) | 11);  // lsum: pair-11 hi half
        float inv = 1.f / denom;
        lpatch[rr * 32 + n]      = s0 * inv;
        lpatch[rr * 32 + 16 + n] = s1 * inv;
    }
    __syncthreads();

    if (tid < 192) {                             // 3 channels x 64 pixels
        int c = tid >> 6, pix = tid & 63;
        int h = h0 + (pix >> 3), w = w0 + (pix & 7);
        float sum = 0.f; int cnt = 0;
#pragma unroll
        for (int r1 = 0; r1 < 3; ++r1) {
            int I = h - r1; if ((unsigned)I >= 126u) continue;
#pragma unroll
            for (int r2 = 0; r2 < 3; ++r2) {
                int J = w - r2; if ((unsigned)J >= 126u) continue;
                int rr = (I - (h0 - 2)) * 10 + (J - (w0 - 2));
                sum += lpatch[rr * 32 + c * 9 + r1 * 3 + r2];
                ++cnt;
            }
        }
        out[c * 16384 + h * 128 + w] = sum / (float)cnt;
    }
}

// ---------------------------------------------------------------------------
extern "C" void kernel_launch(void* const* d_in, const int* in_sizes, int n_in,
                              void* d_out, int out_size, void* d_ws, size_t ws_size,
                              hipStream_t stream)
{
    const float* x = (const float*)d_in[0];
    const float* y = (const float*)d_in[1];
    float* out = (float*)d_out;

    // ws layout (13 MB)
    unsigned short* khi = (unsigned short*)d_ws;          // LP*32 u16 (1 MB)
    unsigned short* klo = khi + (size_t)LP * 32;          // 1 MB
    unsigned short* qhi = klo + (size_t)LP * 32;          // 1 MB
    unsigned short* qlo = qhi + (size_t)LQP * 32;         // 1 MB
    unsigned short* vt  = qlo + (size_t)LQP * 32;         // 1 MB (dim-major, permuted)
    unsigned int* opart = (unsigned int*)(vt + (size_t)32 * LP); // 8 MB [row][ch][16]

    dim3 blk(256);
    prep_kernel <<<dim3(384),     blk, 0, stream>>>(x, y, khi, klo, qhi, qlo, vt);
    attn_kernel <<<dim3(64, NCH), blk, 0, stream>>>(khi, klo, qhi, qlo, vt, opart);
    final_kernel<<<dim3(256),     blk, 0, stream>>>(opart, out);
}

// Round 14
// 121.444 us; speedup vs baseline: 2.2744x; 1.0009x over previous
//
#include <hip/hip_runtime.h>

// Non-local attention, B=1,C=3,H=W=128,k=3 -> L=15876 patches, d=27
#define LQv  15876
#define LP   16384              // padded keys: 1024 tiles of 16
#define LQP  16384              // padded queries
#define HOc  126
#define NCH  16                 // attn split-K chunks (1024 keys each)
// exp2-arg = C2L*(q.k) + ck[key] + (80 - CKS*yy)[query] = 80 - CKS*||q-k||^2
// all folded into MFMA pad dims:
//   q dims 0..26 pre-scaled by C2L; key dim27 = ck*IC2L, query dim27 = C2L
//   key dim29 = 1.0, query dim29 = 80 - CKS*yy   (analytic shift)
#define C2L  8.243971662222648f
#define IC2L 0.1213006672795172f
#define CKS  4.121985831111324f

typedef __attribute__((ext_vector_type(8))) short bf16x8;
typedef __attribute__((ext_vector_type(4))) float f32x4;

#define MFMA(a,b,c) __builtin_amdgcn_mfma_f32_16x16x32_bf16((a),(b),(c),0,0,0)
#define EXP2(x) __builtin_amdgcn_exp2f(x)

__device__ __forceinline__ unsigned short f2bf_rne(float f) {
    unsigned u = __float_as_uint(f);
    unsigned r = ((u >> 16) & 1u) + 0x7FFFu;
    return (unsigned short)((u + r) >> 16);
}
__device__ __forceinline__ float bf2f(unsigned short h) {
    return __uint_as_float(((unsigned)h) << 16);
}
__device__ __forceinline__ void split_bf(float v, unsigned short& hi, unsigned short& lo) {
    hi = f2bf_rne(v);
    lo = f2bf_rne(v - bf2f(hi));
}
// compile-time patch-dim -> image offset (relative to i*128+j)
__device__ __forceinline__ constexpr int doffc(int d) {
    return (d / 9) * 16384 + ((d % 9) / 3) * 128 + ((d % 9) % 3);
}

// ---------------------------------------------------------------------------
// R13 POST-MORTEM: the two changes moved OPPOSITE ways. Transposed opart
// bought ~6us in final (residue 63->56.9 -- partly real traffic, not pure
// launch floor). NCH=8 cost ~7us in attn (512 blocks = 2/CU, occupancy
// 29->17%; soft floor below ~2.3 blocks/CU even though MORE occupancy is
// thrice-refuted). Net flat 121.5.
// THIS ROUND: recombine winners. NCH=16 (R8 attn grid, 57.8us proven) +
// transposed opart [row][ch][16] (R13 final gain proven). At NCH=16 each
// patch row is ONE 1KB contiguous run for final. attn epilogue writes 64B
// @ 1KB stride (same pattern as R13 -- attn regression there was fully the
// grid change, per occupancy counter). Everything else verbatim R8.
// ---------------------------------------------------------------------------

// ---------------------------------------------------------------------------
// prep: PAIR-SPLIT over 384 blocks (verbatim R8). Roles (128 blk each):
//   role 0: key bf16 hi/lo rows  role 1: query rows (pre-scaled by C2L)
//   role 2: dim-major V, PERMUTED columns (kappa=16t+4g+i -> slot 8g+4t+i)
// ---------------------------------------------------------------------------
__global__ __launch_bounds__(256) void prep_kernel(
    const float* __restrict__ x, const float* __restrict__ y,
    unsigned short* __restrict__ khi, unsigned short* __restrict__ klo,
    unsigned short* __restrict__ qhi, unsigned short* __restrict__ qlo,
    unsigned short* __restrict__ vt)
{
    int gidx = blockIdx.x * 256 + threadIdx.x;   // 384*256 = 98304 threads
    int pair = gidx >> 1, half = gidx & 1;
    int l = pair & (LP - 1);
    int role = pair >> 14;                       // block-uniform (128 blk/role)
    bool real = l < LQv;
    int i = real ? (l / HOc) : 0, j = real ? (l - i * HOc) : 0;
    int base = i * 128 + j;

    if (role < 2) {
        const float* __restrict__ src = role ? y : x;
        float scale = role ? C2L : 1.f;
        __align__(16) unsigned short hh[16], ll[16];
        float ss = 0.f;
#pragma unroll
        for (int it = 0; it < 16; ++it) {
            int offL = doffc(it);
            int offH = (16 + it < 27) ? doffc(16 + it) : 0;
            int off  = half ? offH : offL;
            bool ok  = (it < 11) ? real : (real && !half);
            float v = src[base + off];
            v = ok ? v : 0.f;
            ss = fmaf(v, v, ss);
            split_bf(scale * v, hh[it], ll[it]);
        }
        float tot = ss + __shfl_xor(ss, 1);      // full ||row||^2
        if (half) {                              // pad dims 27..31 = idx 11..15
            if (role == 0) {
                float ckv = real ? (-tot * CKS) : -1e30f;  // pad keys -> p=0
                split_bf(ckv * IC2L, hh[11], ll[11]);
                hh[12] = ll[12] = 0;
                hh[13] = 0x3F80; ll[13] = 0;     // bf16(1.0)
                hh[14] = ll[14] = 0; hh[15] = ll[15] = 0;
            } else {
                split_bf(C2L, hh[11], ll[11]);
                hh[12] = ll[12] = 0;
                split_bf(80.f - CKS * tot, hh[13], ll[13]);  // analytic shift
                hh[14] = ll[14] = 0; hh[15] = ll[15] = 0;
            }
        }
        int d0 = half << 4;
        unsigned short* dh = (role ? qhi : khi) + (size_t)l * 32 + d0;
        unsigned short* dl = (role ? qlo : klo) + (size_t)l * 32 + d0;
        ((uint4*)dh)[0] = ((uint4*)hh)[0]; ((uint4*)dh)[1] = ((uint4*)hh)[1];
        ((uint4*)dl)[0] = ((uint4*)ll)[0]; ((uint4*)dl)[1] = ((uint4*)ll)[1];
    } else {                                     // ---- permuted Vt
        int kap = l & 31;
        int cp = 8 * ((kap >> 2) & 3) + 4 * (kap >> 4) + (kap & 3);
        int lp = (l & ~31) | cp;
        unsigned short* vbase = vt + lp + (half ? 16 * LP : 0);
#pragma unroll
        for (int it = 0; it < 16; ++it) {
            int offL = doffc(it);
            int offH = (16 + it < 27) ? doffc(16 + it) : 0;
            int off  = half ? offH : offL;
            bool ok  = (it < 11) ? real : (real && !half);
            float xv = x[base + off];
            unsigned short v;
            if (it == 11)  // half1 col 27: ones row -> lsum column
                v = ok ? f2bf_rne(xv) : ((real && half) ? (unsigned short)0x3F80
                                                        : (unsigned short)0);
            else
                v = ok ? f2bf_rne(xv) : 0;
            vbase[it * LP] = v;
        }
    }
}

// ---------------------------------------------------------------------------
// attn: R8-proven body. QT=4, LDS double-buffered 64-key tiles, T2 swizzle
// (conflicts 0), one barrier per tile, grid (64,16) = 1024 blocks.
// Epilogue writes TRANSPOSED opart [row][ch][16].
// ---------------------------------------------------------------------------
__device__ __forceinline__ void gload16(const unsigned short* g, unsigned short* l)
{
    // lds dest = wave-uniform base + lane*16B; global src is per-lane
    __builtin_amdgcn_global_load_lds(
        (__attribute__((address_space(1))) void*)g,
        (__attribute__((address_space(3))) void*)l, 16, 0, 0);
}

// swizzled per-lane source offset (u16 units) for row-major K segments:
// row R=lane>>2 keeps its 32-u16 row; 8-u16 chunk C=lane&3 XOR s(R)=(lane>>3)&3
#define SLANE8(lane) ((((lane) & ~3) | (((lane) & 3) ^ (((lane) >> 3) & 3))) * 8)
// chunk-only swizzle for vt (row picked separately)
#define SCHUNK8(lane) ((((lane) & 3) ^ (((lane) >> 3) & 3)) * 8)

__global__ __launch_bounds__(256, 4) void attn_kernel(
    const unsigned short* __restrict__ khi, const unsigned short* __restrict__ klo,
    const unsigned short* __restrict__ qhi, const unsigned short* __restrict__ qlo,
    const unsigned short* __restrict__ vt,  unsigned int* __restrict__ opart)
{
    // 64-key buffer: khi [64][32] @0, klo @2048, vt 2x[32][32] @4096/@5120
    __shared__ __align__(16) unsigned short lds[2][6144];  // 24 KB
    int lane = threadIdx.x & 63;
    int wave = threadIdx.x >> 6;
    int n = lane & 15, g = lane >> 4;
    int gx = g ^ ((n >> 1) & 3);                 // swizzled read chunk
    int qb = blockIdx.x * 256 + wave * 64;
    int ch = blockIdx.y;

    bf16x8 bqh[4], bql[4];
#pragma unroll
    for (int t = 0; t < 4; ++t) {
        bqh[t] = *(const bf16x8*)(qhi + (size_t)(qb + t * 16 + n) * 32 + g * 8);
        bql[t] = *(const bf16x8*)(qlo + (size_t)(qb + t * 16 + n) * 32 + g * 8);
    }

    f32x4 o0[4], o1[4];
#pragma unroll
    for (int t = 0; t < 4; ++t) {
        o0[t] = (f32x4){0.f, 0.f, 0.f, 0.f};
        o1[t] = (f32x4){0.f, 0.f, 0.f, 0.f};
    }

    int kb0 = ch * 1024;                         // 1024 keys per chunk

    // ---- stage one 64-key tile (12KB) into dst; 12 x 1KB segments split by
    // wave (w0: khi x4, w1: klo x4, w2: vt half0 x2, w3: vt half1 x2).
    // LDS dest linear (lane*16B); source carries the inverse swizzle.
#define STAGE(dst, kb) do {                                                   \
        if (wave == 0) {                                                      \
            gload16(khi + (size_t)(kb) * 32 +        SLANE8(lane), (dst));    \
            gload16(khi + (size_t)(kb) * 32 +  512 + SLANE8(lane), (dst) + 512);\
            gload16(khi + (size_t)(kb) * 32 + 1024 + SLANE8(lane), (dst) + 1024);\
            gload16(khi + (size_t)(kb) * 32 + 1536 + SLANE8(lane), (dst) + 1536);\
        } else if (wave == 1) {                                               \
            gload16(klo + (size_t)(kb) * 32 +        SLANE8(lane), (dst) + 2048);\
            gload16(klo + (size_t)(kb) * 32 +  512 + SLANE8(lane), (dst) + 2560);\
            gload16(klo + (size_t)(kb) * 32 + 1024 + SLANE8(lane), (dst) + 3072);\
            gload16(klo + (size_t)(kb) * 32 + 1536 + SLANE8(lane), (dst) + 3584);\
        } else if (wave == 2) {                                               \
            gload16(vt + (size_t)(lane >> 2) * LP + (kb) + SCHUNK8(lane),     \
                    (dst) + 4096);                                            \
            gload16(vt + (size_t)(16 + (lane >> 2)) * LP + (kb) + SCHUNK8(lane), \
                    (dst) + 4608);                                            \
        } else {                                                              \
            gload16(vt + (size_t)(lane >> 2) * LP + (kb) + 32 + SCHUNK8(lane),\
                    (dst) + 5120);                                            \
            gload16(vt + (size_t)(16 + (lane >> 2)) * LP + (kb) + 32 + SCHUNK8(lane), \
                    (dst) + 5632);                                            \
        }                                                                     \
    } while (0)

    STAGE(lds[0], kb0);
    __syncthreads();

    int buf = 0;
    for (int it = 0; it < 16; ++it) {            // 16 x 64-key tiles
        // prefetch next tile into the other buffer (wraps at end; dead write)
        int kbn = kb0 + ((it + 1) & 15) * 64;
        STAGE(lds[buf ^ 1], kbn);
        __builtin_amdgcn_sched_barrier(0);       // pin load-issue at region top

        const unsigned short* L = lds[buf];
#pragma unroll
        for (int h = 0; h < 2; ++h) {            // two 32-key halves
            bf16x8 kh0 = *(const bf16x8*)(L + (32 * h + n) * 32 + gx * 8);
            bf16x8 kh1 = *(const bf16x8*)(L + (32 * h + 16 + n) * 32 + gx * 8);
            bf16x8 kl0 = *(const bf16x8*)(L + 2048 + (32 * h + n) * 32 + gx * 8);
            bf16x8 kl1 = *(const bf16x8*)(L + 2048 + (32 * h + 16 + n) * 32 + gx * 8);
            bf16x8 v0  = *(const bf16x8*)(L + 4096 + h * 1024 + n * 32 + gx * 8);
            bf16x8 v1  = *(const bf16x8*)(L + 4096 + h * 1024 + (16 + n) * 32 + gx * 8);

#pragma unroll
            for (int qt = 0; qt < 4; ++qt) {
                f32x4 cc0 = {0.f, 0.f, 0.f, 0.f}, cc1 = {0.f, 0.f, 0.f, 0.f};
                cc0 = MFMA(kh0, bqh[qt], cc0); cc1 = MFMA(kh1, bqh[qt], cc1);
                cc0 = MFMA(kh0, bql[qt], cc0); cc1 = MFMA(kh1, bql[qt], cc1);
                cc0 = MFMA(kl0, bqh[qt], cc0); cc1 = MFMA(kl1, bqh[qt], cc1);
                // accumulator IS the exp2 argument (all consts folded)
                float p0 = EXP2(cc0[0]);
                float p1 = EXP2(cc0[1]);
                float p2 = EXP2(cc0[2]);
                float p3 = EXP2(cc0[3]);
                float p4 = EXP2(cc1[0]);
                float p5 = EXP2(cc1[1]);
                float p6 = EXP2(cc1[2]);
                float p7 = EXP2(cc1[3]);
                // packed p-pairs ARE the PV A-fragment (Vt columns permuted)
                union { unsigned u[4]; bf16x8 v; } ap;
                ap.u[0] = __builtin_amdgcn_perm(__float_as_uint(p1), __float_as_uint(p0), 0x07060302u);
                ap.u[1] = __builtin_amdgcn_perm(__float_as_uint(p3), __float_as_uint(p2), 0x07060302u);
                ap.u[2] = __builtin_amdgcn_perm(__float_as_uint(p5), __float_as_uint(p4), 0x07060302u);
                ap.u[3] = __builtin_amdgcn_perm(__float_as_uint(p7), __float_as_uint(p6), 0x07060302u);
                o0[qt] = MFMA(ap.v, v0, o0[qt]);
                o1[qt] = MFMA(ap.v, v1, o1[qt]);
            }
        }
        __syncthreads();      // one vmcnt+lgkm drain per 64-key tile
        buf ^= 1;
    }
#undef STAGE

    // epilogue: bf16-pack partials, TRANSPOSED layout [row][ch][16]
#pragma unroll
    for (int qt = 0; qt < 4; ++qt) {
#pragma unroll
        for (int r = 0; r < 4; ++r) {
            unsigned w = ((unsigned)f2bf_rne(o1[qt][r]) << 16) | f2bf_rne(o0[qt][r]);
            size_t row = (size_t)(qb + qt * 16 + 4 * g + r);
            opart[(row * NCH + ch) * 16 + n] = w;
        }
    }
}

// ---------------------------------------------------------------------------
// final: FUSED merge + overlap-add (R8 structure). With transposed opart,
// each task's chunk-loop reads one contiguous 1KB run per patch row l.
// ---------------------------------------------------------------------------
__global__ __launch_bounds__(256) void final_kernel(
    const unsigned int* __restrict__ opart, float* __restrict__ out)
{
    __shared__ float lpatch[100 * 32];           // 10x10 rows x 32 cols (12.8 KB)
    int tid = threadIdx.x;
    int lane = tid & 63;
    int h0 = (blockIdx.x >> 4) * 8, w0 = (blockIdx.x & 15) * 8;

    for (int t = tid; t < 1600; t += 256) {      // 100 rows x 16 pairs
        int rr = t >> 4, n = t & 15;
        int di = rr / 10, dj = rr - di * 10;
        int I = h0 - 2 + di, J = w0 - 2 + dj;
        bool valid = ((unsigned)I < 126u) && ((unsigned)J < 126u);
        int l = valid ? (I * HOc + J) : 0;       // clamped row never read
        float s0 = 0.f, s1 = 0.f;
#pragma unroll
        for (int c = 0; c < NCH; ++c) {
            unsigned v = opart[((size_t)l * NCH + c) * 16 + n];
            s0 += bf2f((unsigned short)(v & 0xffffu));
            s1 += bf2f((unsigned short)(v >> 16));
        }
        float denom = __shfl(s1, (lane & 48) | 11);  // lsum: pair-11 hi half
        float inv = 1.f / denom;
        lpatch[rr * 32 + n]      = s0 * inv;
        lpatch[rr * 32 + 16 + n] = s1 * inv;
    }
    __syncthreads();

    if (tid < 192) {                             // 3 channels x 64 pixels
        int c = tid >> 6, pix = tid & 63;
        int h = h0 + (pix >> 3), w = w0 + (pix & 7);
        float sum = 0.f; int cnt = 0;
#pragma unroll
        for (int r1 = 0; r1 < 3; ++r1) {
            int I = h - r1; if ((unsigned)I >= 126u) continue;
#pragma unroll
            for (int r2 = 0; r2 < 3; ++r2) {
                int J = w - r2; if ((unsigned)J >= 126u) continue;
                int rr = (I - (h0 - 2)) * 10 + (J - (w0 - 2));
                sum += lpatch[rr * 32 + c * 9 + r1 * 3 + r2];
                ++cnt;
            }
        }
        out[c * 16384 + h * 128 + w] = sum / (float)cnt;
    }
}

// ---------------------------------------------------------------------------
extern "C" void kernel_launch(void* const* d_in, const int* in_sizes, int n_in,
                              void* d_out, int out_size, void* d_ws, size_t ws_size,
                              hipStream_t stream)
{
    const float* x = (const float*)d_in[0];
    const float* y = (const float*)d_in[1];
    float* out = (float*)d_out;

    // ws layout (21 MB)
    unsigned short* khi = (unsigned short*)d_ws;          // LP*32 u16 (1 MB)
    unsigned short* klo = khi + (size_t)LP * 32;          // 1 MB
    unsigned short* qhi = klo + (size_t)LP * 32;          // 1 MB
    unsigned short* qlo = qhi + (size_t)LQP * 32;         // 1 MB
    unsigned short* vt  = qlo + (size_t)LQP * 32;         // 1 MB (dim-major, permuted)
    unsigned int* opart = (unsigned int*)(vt + (size_t)32 * LP); // 16 MB [row][ch][16]

    dim3 blk(256);
    prep_kernel <<<dim3(384),     blk, 0, stream>>>(x, y, khi, klo, qhi, qlo, vt);
    attn_kernel <<<dim3(64, NCH), blk, 0, stream>>>(khi, klo, qhi, qlo, vt, opart);
    final_kernel<<<dim3(256),     blk, 0, stream>>>(opart, out);
}

// Round 15
// 120.047 us; speedup vs baseline: 2.3009x; 1.0116x over previous
//
#include <hip/hip_runtime.h>

// Non-local attention, B=1,C=3,H=W=128,k=3 -> L=15876 patches, d=27
#define LQv  15876
#define LP   16384              // padded keys: 1024 tiles of 16
#define LQP  16384              // padded queries
#define HOc  126
#define NCH  16                 // attn split-K chunks (1024 keys each)
// exp2-arg = C2L*(q.k) + ck[key] + (80 - CKS*yy)[query] = 80 - CKS*||q-k||^2
// all folded into MFMA pad dims:
//   q dims 0..26 pre-scaled by C2L; key dim27 = ck*IC2L, query dim27 = C2L
//   key dim29 = 1.0, query dim29 = 80 - CKS*yy   (analytic shift)
#define C2L  8.243971662222648f
#define IC2L 0.1213006672795172f
#define CKS  4.121985831111324f

typedef __attribute__((ext_vector_type(8))) short bf16x8;
typedef __attribute__((ext_vector_type(4))) float f32x4;

#define MFMA(a,b,c) __builtin_amdgcn_mfma_f32_16x16x32_bf16((a),(b),(c),0,0,0)
#define EXP2(x) __builtin_amdgcn_exp2f(x)

__device__ __forceinline__ unsigned short f2bf_rne(float f) {
    unsigned u = __float_as_uint(f);
    unsigned r = ((u >> 16) & 1u) + 0x7FFFu;
    return (unsigned short)((u + r) >> 16);
}
__device__ __forceinline__ float bf2f(unsigned short h) {
    return __uint_as_float(((unsigned)h) << 16);
}
__device__ __forceinline__ void split_bf(float v, unsigned short& hi, unsigned short& lo) {
    hi = f2bf_rne(v);
    lo = f2bf_rne(v - bf2f(hi));
}
// compile-time patch-dim -> image offset (relative to i*128+j)
__device__ __forceinline__ constexpr int doffc(int d) {
    return (d / 9) * 16384 + ((d % 9) / 3) * 128 + ((d % 9) % 3);
}

// ---------------------------------------------------------------------------
// R14 POST-MORTEM: transpose was NEUTRAL (R13's 6us residue gain was purely
// opart 16->8MB; R8 63.0 vs R14 63.4 residue at same 16MB). Fixed overhead
// ~45-58us proven by R12's single-kernel total-vs-dur gap. Controllable:
// attn 58 + final ~13 + prep ~5.
// THIS ROUND: the one untried attn discriminator. Guide claims "MFMA blocks
// its wave" -- if literal, the 50/50-serial signature is just program order
// and intra-wave overlap is impossible. Test: EXPLICIT software pipeline of
// the 8 (h,qt) groups per tile: issue group g+1's 6 QK MFMAs BEFORE group
// g's exp2/perm/PV (its accumulator completed a full group ago), with
// sched_barrier(0) at group-cluster granularity (not m141's per-instr
// pinning) so the scheduler cannot re-serialize. Math bit-identical (same
// ops, reordered across independent groups). Needs 2x cc state + both
// halves' K/V live: ~148 VGPR -> launch_bounds(256,3) (cap ~168; R8 only
// achieved 2.3 blocks/CU anyway).
// Verify: VGPR 130-165, WRITE 16.4MB (no spill). Overlap -> sum>110, attn
// 44-50. Flat -> guide claim literal, serial bound structural -> converged.
// ---------------------------------------------------------------------------

// ---------------------------------------------------------------------------
// prep: PAIR-SPLIT over 384 blocks (verbatim R8). Roles (128 blk each):
//   role 0: key bf16 hi/lo rows  role 1: query rows (pre-scaled by C2L)
//   role 2: dim-major V, PERMUTED columns (kappa=16t+4g+i -> slot 8g+4t+i)
// ---------------------------------------------------------------------------
__global__ __launch_bounds__(256) void prep_kernel(
    const float* __restrict__ x, const float* __restrict__ y,
    unsigned short* __restrict__ khi, unsigned short* __restrict__ klo,
    unsigned short* __restrict__ qhi, unsigned short* __restrict__ qlo,
    unsigned short* __restrict__ vt)
{
    int gidx = blockIdx.x * 256 + threadIdx.x;   // 384*256 = 98304 threads
    int pair = gidx >> 1, half = gidx & 1;
    int l = pair & (LP - 1);
    int role = pair >> 14;                       // block-uniform (128 blk/role)
    bool real = l < LQv;
    int i = real ? (l / HOc) : 0, j = real ? (l - i * HOc) : 0;
    int base = i * 128 + j;

    if (role < 2) {
        const float* __restrict__ src = role ? y : x;
        float scale = role ? C2L : 1.f;
        __align__(16) unsigned short hh[16], ll[16];
        float ss = 0.f;
#pragma unroll
        for (int it = 0; it < 16; ++it) {
            int offL = doffc(it);
            int offH = (16 + it < 27) ? doffc(16 + it) : 0;
            int off  = half ? offH : offL;
            bool ok  = (it < 11) ? real : (real && !half);
            float v = src[base + off];
            v = ok ? v : 0.f;
            ss = fmaf(v, v, ss);
            split_bf(scale * v, hh[it], ll[it]);
        }
        float tot = ss + __shfl_xor(ss, 1);      // full ||row||^2
        if (half) {                              // pad dims 27..31 = idx 11..15
            if (role == 0) {
                float ckv = real ? (-tot * CKS) : -1e30f;  // pad keys -> p=0
                split_bf(ckv * IC2L, hh[11], ll[11]);
                hh[12] = ll[12] = 0;
                hh[13] = 0x3F80; ll[13] = 0;     // bf16(1.0)
                hh[14] = ll[14] = 0; hh[15] = ll[15] = 0;
            } else {
                split_bf(C2L, hh[11], ll[11]);
                hh[12] = ll[12] = 0;
                split_bf(80.f - CKS * tot, hh[13], ll[13]);  // analytic shift
                hh[14] = ll[14] = 0; hh[15] = ll[15] = 0;
            }
        }
        int d0 = half << 4;
        unsigned short* dh = (role ? qhi : khi) + (size_t)l * 32 + d0;
        unsigned short* dl = (role ? qlo : klo) + (size_t)l * 32 + d0;
        ((uint4*)dh)[0] = ((uint4*)hh)[0]; ((uint4*)dh)[1] = ((uint4*)hh)[1];
        ((uint4*)dl)[0] = ((uint4*)ll)[0]; ((uint4*)dl)[1] = ((uint4*)ll)[1];
    } else {                                     // ---- permuted Vt
        int kap = l & 31;
        int cp = 8 * ((kap >> 2) & 3) + 4 * (kap >> 4) + (kap & 3);
        int lp = (l & ~31) | cp;
        unsigned short* vbase = vt + lp + (half ? 16 * LP : 0);
#pragma unroll
        for (int it = 0; it < 16; ++it) {
            int offL = doffc(it);
            int offH = (16 + it < 27) ? doffc(16 + it) : 0;
            int off  = half ? offH : offL;
            bool ok  = (it < 11) ? real : (real && !half);
            float xv = x[base + off];
            unsigned short v;
            if (it == 11)  // half1 col 27: ones row -> lsum column
                v = ok ? f2bf_rne(xv) : ((real && half) ? (unsigned short)0x3F80
                                                        : (unsigned short)0);
            else
                v = ok ? f2bf_rne(xv) : 0;
            vbase[it * LP] = v;
        }
    }
}

// ---------------------------------------------------------------------------
// attn: R8 staging/swizzle + SOFTWARE-PIPELINED (h,qt) groups.
// Per 64-key tile: 8 groups g=(h,qt). QK(g+1) issued before SM_PV(g);
// sched_barrier(0) between clusters pins the interleave. cc double-buffered
// (cA/cB); all 12 K/V regs live (compile-time indexed). Epilogue writes
// transposed opart [row][ch][16] (neutral for attn, keeps final contiguous).
// ---------------------------------------------------------------------------
__device__ __forceinline__ void gload16(const unsigned short* g, unsigned short* l)
{
    // lds dest = wave-uniform base + lane*16B; global src is per-lane
    __builtin_amdgcn_global_load_lds(
        (__attribute__((address_space(1))) void*)g,
        (__attribute__((address_space(3))) void*)l, 16, 0, 0);
}

// swizzled per-lane source offset (u16 units) for row-major K segments:
// row R=lane>>2 keeps its 32-u16 row; 8-u16 chunk C=lane&3 XOR s(R)=(lane>>3)&3
#define SLANE8(lane) ((((lane) & ~3) | (((lane) & 3) ^ (((lane) >> 3) & 3))) * 8)
// chunk-only swizzle for vt (row picked separately)
#define SCHUNK8(lane) ((((lane) & 3) ^ (((lane) >> 3) & 3)) * 8)

__global__ __launch_bounds__(256, 3) void attn_kernel(
    const unsigned short* __restrict__ khi, const unsigned short* __restrict__ klo,
    const unsigned short* __restrict__ qhi, const unsigned short* __restrict__ qlo,
    const unsigned short* __restrict__ vt,  unsigned int* __restrict__ opart)
{
    // 64-key buffer: khi [64][32] @0, klo @2048, vt 2x[32][32] @4096/@5120
    __shared__ __align__(16) unsigned short lds[2][6144];  // 24 KB
    int lane = threadIdx.x & 63;
    int wave = threadIdx.x >> 6;
    int n = lane & 15, g = lane >> 4;
    int gx = g ^ ((n >> 1) & 3);                 // swizzled read chunk
    int qb = blockIdx.x * 256 + wave * 64;
    int ch = blockIdx.y;

    bf16x8 bqh[4], bql[4];
#pragma unroll
    for (int t = 0; t < 4; ++t) {
        bqh[t] = *(const bf16x8*)(qhi + (size_t)(qb + t * 16 + n) * 32 + g * 8);
        bql[t] = *(const bf16x8*)(qlo + (size_t)(qb + t * 16 + n) * 32 + g * 8);
    }

    f32x4 o0[4], o1[4];
#pragma unroll
    for (int t = 0; t < 4; ++t) {
        o0[t] = (f32x4){0.f, 0.f, 0.f, 0.f};
        o1[t] = (f32x4){0.f, 0.f, 0.f, 0.f};
    }

    int kb0 = ch * 1024;                         // 1024 keys per chunk

    // ---- stage one 64-key tile (12KB) into dst; 12 x 1KB segments split by
    // wave (w0: khi x4, w1: klo x4, w2: vt half0 x2, w3: vt half1 x2).
    // LDS dest linear (lane*16B); source carries the inverse swizzle.
#define STAGE(dst, kb) do {                                                   \
        if (wave == 0) {                                                      \
            gload16(khi + (size_t)(kb) * 32 +        SLANE8(lane), (dst));    \
            gload16(khi + (size_t)(kb) * 32 +  512 + SLANE8(lane), (dst) + 512);\
            gload16(khi + (size_t)(kb) * 32 + 1024 + SLANE8(lane), (dst) + 1024);\
            gload16(khi + (size_t)(kb) * 32 + 1536 + SLANE8(lane), (dst) + 1536);\
        } else if (wave == 1) {                                               \
            gload16(klo + (size_t)(kb) * 32 +        SLANE8(lane), (dst) + 2048);\
            gload16(klo + (size_t)(kb) * 32 +  512 + SLANE8(lane), (dst) + 2560);\
            gload16(klo + (size_t)(kb) * 32 + 1024 + SLANE8(lane), (dst) + 3072);\
            gload16(klo + (size_t)(kb) * 32 + 1536 + SLANE8(lane), (dst) + 3584);\
        } else if (wave == 2) {                                               \
            gload16(vt + (size_t)(lane >> 2) * LP + (kb) + SCHUNK8(lane),     \
                    (dst) + 4096);                                            \
            gload16(vt + (size_t)(16 + (lane >> 2)) * LP + (kb) + SCHUNK8(lane), \
                    (dst) + 4608);                                            \
        } else {                                                              \
            gload16(vt + (size_t)(lane >> 2) * LP + (kb) + 32 + SCHUNK8(lane),\
                    (dst) + 5120);                                            \
            gload16(vt + (size_t)(16 + (lane >> 2)) * LP + (kb) + 32 + SCHUNK8(lane), \
                    (dst) + 5632);                                            \
        }                                                                     \
    } while (0)

    // ---- pipelined group macros: QK issue cluster / softmax+PV cluster ----
#define SBAR __builtin_amdgcn_sched_barrier(0)
#define QK_GRP(CC0, CC1, H, QT) do {                                          \
        CC0 = (f32x4){0.f, 0.f, 0.f, 0.f};                                    \
        CC1 = (f32x4){0.f, 0.f, 0.f, 0.f};                                    \
        CC0 = MFMA(KH[H][0], bqh[QT], CC0); CC1 = MFMA(KH[H][1], bqh[QT], CC1);\
        CC0 = MFMA(KH[H][0], bql[QT], CC0); CC1 = MFMA(KH[H][1], bql[QT], CC1);\
        CC0 = MFMA(KL[H][0], bqh[QT], CC0); CC1 = MFMA(KL[H][1], bqh[QT], CC1);\
    } while (0)
#define SM_PV(CC0, CC1, H, QT) do {                                           \
        float p0 = EXP2(CC0[0]); float p1 = EXP2(CC0[1]);                     \
        float p2 = EXP2(CC0[2]); float p3 = EXP2(CC0[3]);                     \
        float p4 = EXP2(CC1[0]); float p5 = EXP2(CC1[1]);                     \
        float p6 = EXP2(CC1[2]); float p7 = EXP2(CC1[3]);                     \
        union { unsigned u[4]; bf16x8 v; } ap;                                \
        ap.u[0] = __builtin_amdgcn_perm(__float_as_uint(p1), __float_as_uint(p0), 0x07060302u); \
        ap.u[1] = __builtin_amdgcn_perm(__float_as_uint(p3), __float_as_uint(p2), 0x07060302u); \
        ap.u[2] = __builtin_amdgcn_perm(__float_as_uint(p5), __float_as_uint(p4), 0x07060302u); \
        ap.u[3] = __builtin_amdgcn_perm(__float_as_uint(p7), __float_as_uint(p6), 0x07060302u); \
        o0[QT] = MFMA(ap.v, VV[H][0], o0[QT]);                                \
        o1[QT] = MFMA(ap.v, VV[H][1], o1[QT]);                                \
    } while (0)

    STAGE(lds[0], kb0);
    __syncthreads();

    int buf = 0;
    for (int it = 0; it < 16; ++it) {            // 16 x 64-key tiles
        // prefetch next tile into the other buffer (wraps at end; dead write)
        int kbn = kb0 + ((it + 1) & 15) * 64;
        STAGE(lds[buf ^ 1], kbn);
        __builtin_amdgcn_sched_barrier(0);       // pin load-issue at region top

        const unsigned short* L = lds[buf];
        // both halves' K/V in registers (compile-time indices; SBARs below
        // prevent the R9 re-sink -- reads can't cross group fences)
        bf16x8 KH[2][2], KL[2][2], VV[2][2];
#pragma unroll
        for (int h = 0; h < 2; ++h) {
            KH[h][0] = *(const bf16x8*)(L + (32 * h + n) * 32 + gx * 8);
            KH[h][1] = *(const bf16x8*)(L + (32 * h + 16 + n) * 32 + gx * 8);
            KL[h][0] = *(const bf16x8*)(L + 2048 + (32 * h + n) * 32 + gx * 8);
            KL[h][1] = *(const bf16x8*)(L + 2048 + (32 * h + 16 + n) * 32 + gx * 8);
            VV[h][0] = *(const bf16x8*)(L + 4096 + h * 1024 + n * 32 + gx * 8);
            VV[h][1] = *(const bf16x8*)(L + 4096 + h * 1024 + (16 + n) * 32 + gx * 8);
        }

        // software pipeline: QK(g+1) issued before SM_PV(g) consumes cc(g)
        f32x4 cA0, cA1, cB0, cB1;
        QK_GRP(cA0, cA1, 0, 0);                               SBAR;
        QK_GRP(cB0, cB1, 0, 1); SBAR; SM_PV(cA0, cA1, 0, 0);  SBAR;
        QK_GRP(cA0, cA1, 0, 2); SBAR; SM_PV(cB0, cB1, 0, 1);  SBAR;
        QK_GRP(cB0, cB1, 0, 3); SBAR; SM_PV(cA0, cA1, 0, 2);  SBAR;
        QK_GRP(cA0, cA1, 1, 0); SBAR; SM_PV(cB0, cB1, 0, 3);  SBAR;
        QK_GRP(cB0, cB1, 1, 1); SBAR; SM_PV(cA0, cA1, 1, 0);  SBAR;
        QK_GRP(cA0, cA1, 1, 2); SBAR; SM_PV(cB0, cB1, 1, 1);  SBAR;
        QK_GRP(cB0, cB1, 1, 3); SBAR; SM_PV(cA0, cA1, 1, 2);  SBAR;
        SM_PV(cB0, cB1, 1, 3);

        __syncthreads();      // one vmcnt+lgkm drain per 64-key tile
        buf ^= 1;
    }
#undef STAGE
#undef QK_GRP
#undef SM_PV
#undef SBAR

    // epilogue: bf16-pack partials, TRANSPOSED layout [row][ch][16]
#pragma unroll
    for (int qt = 0; qt < 4; ++qt) {
#pragma unroll
        for (int r = 0; r < 4; ++r) {
            unsigned w = ((unsigned)f2bf_rne(o1[qt][r]) << 16) | f2bf_rne(o0[qt][r]);
            size_t row = (size_t)(qb + qt * 16 + 4 * g + r);
            opart[(row * NCH + ch) * 16 + n] = w;
        }
    }
}

// ---------------------------------------------------------------------------
// final: FUSED merge + overlap-add (R8 structure). With transposed opart,
// each task's chunk-loop reads one contiguous 1KB run per patch row l.
// ---------------------------------------------------------------------------
__global__ __launch_bounds__(256) void final_kernel(
    const unsigned int* __restrict__ opart, float* __restrict__ out)
{
    __shared__ float lpatch[100 * 32];           // 10x10 rows x 32 cols (12.8 KB)
    int tid = threadIdx.x;
    int lane = tid & 63;
    int h0 = (blockIdx.x >> 4) * 8, w0 = (blockIdx.x & 15) * 8;

    for (int t = tid; t < 1600; t += 256) {      // 100 rows x 16 pairs
        int rr = t >> 4, n = t & 15;
        int di = rr / 10, dj = rr - di * 10;
        int I = h0 - 2 + di, J = w0 - 2 + dj;
        bool valid = ((unsigned)I < 126u) && ((unsigned)J < 126u);
        int l = valid ? (I * HOc + J) : 0;       // clamped row never read
        float s0 = 0.f, s1 = 0.f;
#pragma unroll
        for (int c = 0; c < NCH; ++c) {
            unsigned v = opart[((size_t)l * NCH + c) * 16 + n];
            s0 += bf2f((unsigned short)(v & 0xffffu));
            s1 += bf2f((unsigned short)(v >> 16));
        }
        float denom = __shfl(s1, (lane & 48) | 11);  // lsum: pair-11 hi half
        float inv = 1.f / denom;
        lpatch[rr * 32 + n]      = s0 * inv;
        lpatch[rr * 32 + 16 + n] = s1 * inv;
    }
    __syncthreads();

    if (tid < 192) {                             // 3 channels x 64 pixels
        int c = tid >> 6, pix = tid & 63;
        int h = h0 + (pix >> 3), w = w0 + (pix & 7);
        float sum = 0.f; int cnt = 0;
#pragma unroll
        for (int r1 = 0; r1 < 3; ++r1) {
            int I = h - r1; if ((unsigned)I >= 126u) continue;
#pragma unroll
            for (int r2 = 0; r2 < 3; ++r2) {
                int J = w - r2; if ((unsigned)J >= 126u) continue;
                int rr = (I - (h0 - 2)) * 10 + (J - (w0 - 2));
                sum += lpatch[rr * 32 + c * 9 + r1 * 3 + r2];
                ++cnt;
            }
        }
        out[c * 16384 + h * 128 + w] = sum / (float)cnt;
    }
}

// ---------------------------------------------------------------------------
extern "C" void kernel_launch(void* const* d_in, const int* in_sizes, int n_in,
                              void* d_out, int out_size, void* d_ws, size_t ws_size,
                              hipStream_t stream)
{
    const float* x = (const float*)d_in[0];
    const float* y = (const float*)d_in[1];
    float* out = (float*)d_out;

    // ws layout (21 MB)
    unsigned short* khi = (unsigned short*)d_ws;          // LP*32 u16 (1 MB)
    unsigned short* klo = khi + (size_t)LP * 32;          // 1 MB
    unsigned short* qhi = klo + (size_t)LP * 32;          // 1 MB
    unsigned short* qlo = qhi + (size_t)LQP * 32;         // 1 MB
    unsigned short* vt  = qlo + (size_t)LQP * 32;         // 1 MB (dim-major, permuted)
    unsigned int* opart = (unsigned int*)(vt + (size_t)32 * LP); // 16 MB [row][ch][16]

    dim3 blk(256);
    prep_kernel <<<dim3(384),     blk, 0, stream>>>(x, y, khi, klo, qhi, qlo, vt);
    attn_kernel <<<dim3(64, NCH), blk, 0, stream>>>(khi, klo, qhi, qlo, vt, opart);
    final_kernel<<<dim3(256),     blk, 0, stream>>>(opart, out);
}